// Round 11
// baseline (1936.535 us; speedup 1.0000x reference)
//
#include <hip/hip_runtime.h>
#include <hip/hip_bf16.h>

// GRU last-hidden: B=64, T=512, I=256, H=512, fp32 in/out.
// Persistent kernel: 64 WGs x 256 thr.
//
// Round-16 = Round-15 RESUBMIT (previous run died in harness infra —
// "Trio nursery" exception, no pytest/timing output; kernel never judged).
// Deadlock + codegen re-audited: single syncthreads/iter is safe because
// a wave reaches step-t+1 staging only after polling its own WG's other
// waves' tags >= t+2, stored after lgkmcnt(0) covering their hstage
// reads; LDS 17.7KB, 16B-aligned b128 ops, <=2-way bank aliasing (free),
// static register indexing, launch_bounds(256,1).
//
// Theory under test (R15): exchange VOLUME is the only lever that has
// ever moved step time (R6: +4MB/step -> +1.2us/step ~= 3.3TB/s burst;
// R7/R8 latency protocols neutral; R14 de-collision neutral).
// Change vs R5 base: WG = (batch-group g in 0..3, col-group cp in 0..15)
// owns 16 batches x 32 h-cols (was 8 cols x ALL 64 batches). Consumer
// reads only its 16 batches: 16KB/step (was 64KB); total 1MB/step (was
// 4MB). 16KB reg-staged into LDS once per WG; all 4 waves read MFMA
// A-fragments from LDS. Per-wave microstructure identical to R5 (24
// gate-rows x 16 batches x K=512, same weight fragments, same epilogue).
// Sync: per-group tags[g][64]; fan-in 64 -> 16 WGs; groups decoupled.
// Overwrite safety = R5 induction (tag t+2 after vmcnt(0) covering data
// stores + staging loads; lgkmcnt(0) orders hstage reads before publish).
// Replay-safe timestamp init barrier (R11/R13/R14-proven).

#define NB 64
#define NT 512
#define NI 256
#define NH 512

typedef __attribute__((ext_vector_type(8))) short bf16x8;
typedef __attribute__((ext_vector_type(4))) float f32x4;
typedef __attribute__((ext_vector_type(4))) int i32x4;

static __device__ __forceinline__ short f2b(float f) {
  unsigned u = __builtin_bit_cast(unsigned, f);
  unsigned r = (u + 0x7fffu + ((u >> 16) & 1u)) >> 16;
  return (short)r;
}
static __device__ __forceinline__ float sigm(float x) {
  return 1.0f / (1.0f + __expf(-x));
}
static __device__ __forceinline__ float tanh_f(float x) {
  return 1.0f - 2.0f / (__expf(2.0f * x) + 1.0f);
}

__global__ __launch_bounds__(256, 1)
void gru_persistent(const float* __restrict__ x,
                    const float* __restrict__ Wih,
                    const float* __restrict__ Whh,
                    const float* __restrict__ bih,
                    const float* __restrict__ bhh,
                    float* __restrict__ out,
                    unsigned char* __restrict__ ws) {
  const int wg   = blockIdx.x;    // 0..63
  const int tid  = threadIdx.x;   // 0..255
  const int wave = tid >> 6;      // 0..3 : owns cols [cp*32+8w, +8)
  const int lane = tid & 63;
  const int c    = lane & 15;     // A-row (local batch) / B n-index
  const int q    = lane >> 4;     // k-slice quad / C-row group
  const int g    = wg & 3;        // batch group: batches [16g, 16g+16)
  const int cp   = wg >> 2;       // col group:   h-cols  [32cp, 32cp+32)

  const unsigned long long t0 = __builtin_amdgcn_s_memrealtime();

  // ws layout: flags u64[64] stride 64B @0 (4KB); tags int[4][64] @8K
  // (1KB); hb0 @16K (64KB, [64 b][512 col] bf16); hb1 @16K+64K;
  // xb (x as bf16 [b][t][i]) @16K+128K (16MB).
  unsigned long long* flags = (unsigned long long*)ws;
  int* tags = (int*)(ws + 8192);
  unsigned short* hb0 = (unsigned short*)(ws + 16384);
  unsigned short* hb1 = (unsigned short*)(ws + 16384 + 65536);
  unsigned short* xb  = (unsigned short*)(ws + 16384 + 2 * 65536);

  // LDS: staged h for this WG's 16 batches (row stride 520 shorts =
  // 1040B: (addr/4)%32 = (4c+4q)%32 -> c and c+8 alias = 2-way = free),
  // plus the per-wave epilogue transpose bounce.
  __shared__ __align__(16) unsigned short hstage[16][520];
  __shared__ __align__(16) unsigned short trans[4][16][8];

  // ---- prologue: x fp32->bf16, zero h0 and tags ----
  {
    const float4* x4 = (const float4*)x;
    const int total4 = NB * NT * NI / 4;
    const int nthr = NB * 256;
    for (int i = wg * 256 + tid; i < total4; i += nthr) {
      float4 v = x4[i];
      ushort4 o;
      o.x = (unsigned short)f2b(v.x);
      o.y = (unsigned short)f2b(v.y);
      o.z = (unsigned short)f2b(v.z);
      o.w = (unsigned short)f2b(v.w);
      ((ushort4*)xb)[i] = o;
    }
    ((unsigned int*)hb0)[wg * 256 + tid] = 0u;  // h0 = 0 (64KB total)
    if (wg == 0) tags[tid] = 0;                 // 256 tags
  }

  // ---- loop-invariant weight fragments (plain locals; R5 codegen) ----
  // Wave's 24 gate-rows: gate*NH + cp*32 + wave*8 + jj, jj in [0,8).
  bf16x8 wh[2][16];  // W_hh, K=512 -> 16 k-steps
  bf16x8 wi[2][8];   // W_ih, K=256 -> 8 k-steps
#pragma unroll
  for (int nt = 0; nt < 2; nt++) {
    int nl = nt * 16 + c;
    bool valid = nl < 24;
    int gate = nl >> 3;
    int jj = nl & 7;
    int grow = valid ? (gate * NH + cp * 32 + wave * 8 + jj) : 0;
#pragma unroll
    for (int kk = 0; kk < 16; kk++) {
      const float* p = Whh + (size_t)grow * NH + kk * 32 + q * 8;
      bf16x8 f;
#pragma unroll
      for (int e = 0; e < 8; e++) f[e] = valid ? f2b(p[e]) : (short)0;
      wh[nt][kk] = f;
    }
#pragma unroll
    for (int kk = 0; kk < 8; kk++) {
      const float* p = Wih + (size_t)grow * NI + kk * 32 + q * 8;
      bf16x8 f;
#pragma unroll
      for (int e = 0; e < 8; e++) f[e] = valid ? f2b(p[e]) : (short)0;
      wi[nt][kk] = f;
    }
  }

  const int jcol = cp * 32 + wave * 8 + (c & 7);
  const float bri = bih[jcol],          brh = bhh[jcol];
  const float bzi = bih[NH + jcol],     bzh = bhh[NH + jcol];
  const float bni = bih[2 * NH + jcol], bnh = bhh[2 * NH + jcol];

  float hold[4] = {0.f, 0.f, 0.f, 0.f};  // fp32 master state (c<8 lanes)

  // ---- replay-safe timestamp init barrier (proven R11/R13/R14) ----
  __syncthreads();
  if (tid == 0)
    __hip_atomic_store(&flags[wg * 8], __builtin_amdgcn_s_memrealtime(),
                       __ATOMIC_RELEASE, __HIP_MEMORY_SCOPE_AGENT);
  if (wave == 0) {
    while (__hip_atomic_load(&flags[lane * 8], __ATOMIC_RELAXED,
                             __HIP_MEMORY_SCOPE_AGENT) < t0)
      __builtin_amdgcn_s_sleep(1);
  }
  __syncthreads();
  __threadfence();

  const int b0 = g * 16 + c;              // A-row batch for x fragments
  // poll: lane <-> (producer cp'=lane>>2, wave'=lane&3) within group g
  const int* tagp = tags + g * 64 + lane;

  for (int t = 0; t < NT; t++) {
    const unsigned short* hcur = (t & 1) ? hb1 : hb0;
    unsigned short* hnext      = (t & 1) ? hb0 : hb1;

    f32x4 aX0 = {0.f, 0.f, 0.f, 0.f}, aX1 = {0.f, 0.f, 0.f, 0.f};
    f32x4 aH0 = {0.f, 0.f, 0.f, 0.f}, aH1 = {0.f, 0.f, 0.f, 0.f};

    const bf16x8* xr = (const bf16x8*)(xb + ((size_t)b0 * NT + t) * NI);

    // x-projection (cached loads; fills wall-clock while group-g
    // producers publish). Fully before the poll.
#pragma unroll
    for (int kk = 0; kk < 8; kk++) {
      bf16x8 a = xr[kk * 4 + q];
      aX0 = __builtin_amdgcn_mfma_f32_16x16x32_bf16(a, wi[0][kk], aX0, 0, 0, 0);
      aX1 = __builtin_amdgcn_mfma_f32_16x16x32_bf16(a, wi[1][kk], aX1, 0, 0, 0);
    }

    // poll h_t from this group's 16 producers x 4 waves (64 tags).
    if (t > 0) {
      const int need = t + 1;
      for (;;) {
        int v;
        asm volatile("global_load_dword %0, %1, off sc1"
                     : "=v"(v) : "v"(tagp));
        asm volatile("s_waitcnt vmcnt(0)" : "+v"(v)::"memory");
        if (__all(v >= need)) break;
      }
    }

    // stage h[16g..16g+16)[0..512) (16KB) into LDS: 4 sweeps x 256 thr
    // x 16B, reg-staged (global sc1 -> VGPR -> ds_write_b128).
    {
      i32x4 hl0, hl1, hl2, hl3;
      const char* src = (const char*)hcur + (size_t)g * 16384;
      const void* a0 = src + ((size_t)(0 * 256 + tid) << 4);
      const void* a1 = src + ((size_t)(1 * 256 + tid) << 4);
      const void* a2 = src + ((size_t)(2 * 256 + tid) << 4);
      const void* a3 = src + ((size_t)(3 * 256 + tid) << 4);
      asm volatile("global_load_dwordx4 %0, %1, off sc1" : "=v"(hl0) : "v"(a0));
      asm volatile("global_load_dwordx4 %0, %1, off sc1" : "=v"(hl1) : "v"(a1));
      asm volatile("global_load_dwordx4 %0, %1, off sc1" : "=v"(hl2) : "v"(a2));
      asm volatile("global_load_dwordx4 %0, %1, off sc1" : "=v"(hl3) : "v"(a3));
      asm volatile("s_waitcnt vmcnt(0)"
                   : "+v"(hl0), "+v"(hl1), "+v"(hl2), "+v"(hl3) :: "memory");
      // idx = s*256+tid; row = idx>>6 (fixed per wave,sweep); col16 = idx&63
      *(i32x4*)&hstage[(0 * 256 + tid) >> 6][((0 * 256 + tid) & 63) * 8] = hl0;
      *(i32x4*)&hstage[(1 * 256 + tid) >> 6][((1 * 256 + tid) & 63) * 8] = hl1;
      *(i32x4*)&hstage[(2 * 256 + tid) >> 6][((2 * 256 + tid) & 63) * 8] = hl2;
      *(i32x4*)&hstage[(3 * 256 + tid) >> 6][((3 * 256 + tid) & 63) * 8] = hl3;
    }
    __syncthreads();

    // h-projection: A fragments from LDS (row c = local batch).
#pragma unroll
    for (int kk = 0; kk < 16; kk++) {
      bf16x8 a = *(const bf16x8*)&hstage[c][kk * 32 + q * 8];
      aH0 = __builtin_amdgcn_mfma_f32_16x16x32_bf16(a, wh[0][kk], aH0, 0, 0, 0);
      aH1 = __builtin_amdgcn_mfma_f32_16x16x32_bf16(a, wh[1][kk], aH1, 0, 0, 0);
    }

    // epilogue: C/D col=lane&15 (gate-row n), row=q*4+r (local batch).
    // Lane c<8 owns output col cp*32 + wave*8 + c.
#pragma unroll
    for (int r = 0; r < 4; r++) {
      float xz = __shfl_xor(aX0[r], 8, 64);
      float hz = __shfl_xor(aH0[r], 8, 64);
      float rr = sigm(aX0[r] + bri + aH0[r] + brh);
      float zz = sigm(xz + bzi + hz + bzh);
      float nn = tanh_f(aX1[r] + bni + rr * (aH1[r] + bnh));
      float hv2 = (1.0f - zz) * nn + zz * hold[r];
      hold[r] = hv2;
      if (c < 8) trans[wave][q * 4 + r][c] = (unsigned short)f2b(hv2);
    }

    if (t < NT - 1) {
      // publish: wave-local LDS transpose -> one 16B store per lane<16
      // (batch row = lane; byte offset cp*64 + wave*16 within the 1KB
      // row), drain (also re-covers this wave's staging loads), then tag.
      asm volatile("s_waitcnt lgkmcnt(0)" ::: "memory");
      if (lane < 16) {
        i32x4 pk = *(const i32x4*)&trans[wave][lane][0];
        void* dst = (char*)hnext + (size_t)(g * 16 + lane) * 1024 +
                    (size_t)cp * 64 + (size_t)wave * 16;
        asm volatile("global_store_dwordx4 %0, %1, off sc1"
                     :: "v"(dst), "v"(pk) : "memory");
      }
      asm volatile("s_waitcnt vmcnt(0)" ::: "memory");
      if (lane == 0)
        __hip_atomic_store(&tags[g * 64 + cp * 4 + wave], t + 2,
                           __ATOMIC_RELAXED, __HIP_MEMORY_SCOPE_AGENT);
    }
  }

  // final h (fp32 master copy) -> d_out
  if (c < 8) {
#pragma unroll
    for (int r = 0; r < 4; r++) {
      int b = g * 16 + q * 4 + r;
      out[(size_t)b * NH + cp * 32 + wave * 8 + c] = hold[r];
    }
  }
}

extern "C" void kernel_launch(void* const* d_in, const int* in_sizes, int n_in,
                              void* d_out, int out_size, void* d_ws, size_t ws_size,
                              hipStream_t stream) {
  const float* x   = (const float*)d_in[0];
  const float* Wih = (const float*)d_in[1];
  const float* Whh = (const float*)d_in[2];
  const float* bih = (const float*)d_in[3];
  const float* bhh = (const float*)d_in[4];
  float* out = (float*)d_out;
  hipLaunchKernelGGL(gru_persistent, dim3(NB), dim3(256), 0, stream,
                     x, Wih, Whh, bih, bhh, out, (unsigned char*)d_ws);
}